// Round 18
// baseline (129.021 us; speedup 1.0000x reference)
//
#include <hip/hip_runtime.h>

// SparseMCFModel — output `flow` depends ONLY on demands, edge_row, edge_col.
// w_e = 1/deg(row_e) exactly (softmax over identical logits per segment) -> the
// GAT/GRU/decoder pipeline is dead code. Since w depends on row only:
//   flow_j[e] = V_j[row_e],
//   V_1[v] = relu(d[v])/deg[v],
//   V_j[v] = (relu(d[v]) + sum_{e:col=v} V_{j-1}[row_e]) / deg[v],  j=2..10
//   out[e] = V_10[row_e].
//
// r17 (48.3us) + barrier arrive de-serialization: 128 arrivals over 32 padded
// lines (4 same-line RMWs, near-parallel) instead of 8 (16 serialized);
// pollers sum 32 independent dwords (ILP, ~2 overlapped round-trips).
// Setup micro-fix: fill/deg read once per triple, shfl'd to roles 1-2.
// Everything else identical to r17 (best validated state).

#define N_NODES 20000
#define N_EDGES 200000
#define FLOW_ITERS 10
#define NBLK 128
#define NTHR 1024
#define NPB 157                            // nodes per block (128*157 = 20096)
#define CAP 24                             // padded in-edge slots per node
#define NPAIR 100000                       // N_EDGES/2 int2 pairs
#define PPB 782                            // pairs per block (782*128 = 100096)
#define OFL_MAX 4096
#define GLINES 32                          // barrier arrive lines

__device__ __forceinline__ float ld_coh(const float* p) {
    return __hip_atomic_load(p, __ATOMIC_RELAXED, __HIP_MEMORY_SCOPE_AGENT);
}
__device__ __forceinline__ int ld_coh_i(const int* p) {
    return __hip_atomic_load(p, __ATOMIC_RELAXED, __HIP_MEMORY_SCOPE_AGENT);
}
__device__ __forceinline__ void st_coh(float* p, float v) {
    __hip_atomic_store(p, v, __ATOMIC_RELAXED, __HIP_MEMORY_SCOPE_AGENT);
}
__device__ __forceinline__ void st_coh_i(int* p, int v) {
    __hip_atomic_store(p, v, __ATOMIC_RELAXED, __HIP_MEMORY_SCOPE_AGENT);
}

// Distributed-arrival zero-cache-op barrier: arrivals spread over GLINES
// padded lines (4 RMWs/line at NBLK=128 -> near-parallel); pollers sum all
// lines with independent loads. Soundness (r6-r17): __syncthreads drains
// vmcnt before s_barrier; all cross-block mutable data via coherent-point
// ops or fresh-line plain reads.
__device__ __forceinline__ void gbar(int* grp, int ord) {
    __syncthreads();
    if (threadIdx.x == 0) {
        __hip_atomic_fetch_add(&grp[(blockIdx.x & (GLINES - 1)) * 32], 1,
                               __ATOMIC_RELAXED, __HIP_MEMORY_SCOPE_AGENT);
        const int target = NBLK * ord;
        for (;;) {
            int s = 0;
            #pragma unroll
            for (int g = 0; g < GLINES; ++g)
                s += __hip_atomic_load(&grp[g * 32], __ATOMIC_RELAXED,
                                       __HIP_MEMORY_SCOPE_AGENT);
            if (s >= target) break;
            __builtin_amdgcn_s_sleep(1);
        }
    }
    __syncthreads();
}

__global__ __launch_bounds__(NTHR)
void mcf_fused(const float* __restrict__ demands,
               const int* __restrict__ edge_row,   // int2-aligned
               const int* __restrict__ edge_col,
               float* __restrict__ out,
               int* __restrict__ deg,       // [N]   zeroed by memset
               int* __restrict__ fill,      // [N]   zeroed by memset
               float* __restrict__ V0,      // [N]
               float* __restrict__ V1b,     // [N]
               int* __restrict__ pcsc,      // [N*CAP], [v*CAP + k]
               int* __restrict__ ofl_cnt,   // [1]   zeroed by memset
               int* __restrict__ ofl_v,     // [OFL_MAX]
               int* __restrict__ ofl_row,   // [OFL_MAX]
               int* __restrict__ grp)       // [GLINES*32] zeroed by memset
{
    const int tx = threadIdx.x, bx = blockIdx.x;
    int bar = 0;

    // ---- Build: int2 pair loads over 782 threads (12.2 waves of latency
    //      hiding), deg/fill atomics, column-local placement ----
    const int m = bx * PPB + tx;                  // this thread's pair
    const bool bld = (tx < PPB) && (m < NPAIR);
    int2 r2 = {0, 0};
    if (bld) {
        r2 = ((const int2*)edge_row)[m];
        int2 c2 = ((const int2*)edge_col)[m];
        int rr[2] = {r2.x, r2.y};
        int cc[2] = {c2.x, c2.y};
        #pragma unroll
        for (int i = 0; i < 2; ++i) {
            __hip_atomic_fetch_add(&deg[rr[i]], 1, __ATOMIC_RELAXED, __HIP_MEMORY_SCOPE_AGENT);
            int idx = __hip_atomic_fetch_add(&fill[cc[i]], 1,
                                             __ATOMIC_RELAXED, __HIP_MEMORY_SCOPE_AGENT);
            if (idx < CAP) {
                st_coh_i(&pcsc[cc[i] * CAP + idx], rr[i]);
            } else {
                int o = __hip_atomic_fetch_add(ofl_cnt, 1,
                                               __ATOMIC_RELAXED, __HIP_MEMORY_SCOPE_AGENT);
                if (o < OFL_MAX) { st_coh_i(&ofl_v[o], cc[i]); st_coh_i(&ofl_row[o], rr[i]); }
            }
        }
    }
    gbar(grp, ++bar);

    // ---- Role setup: wave-local triples (21 nodes per 63-lane group) ----
    const int wv = tx >> 6, ln = tx & 63;         // wave, lane
    const int t  = ln / 3, q = ln - 3 * t;        // triple, role (lane 63 idle)
    const int g  = wv * 21 + t;                   // node-in-block (16*21=336>=157)
    const int v  = bx * NPB + g;
    const bool active = (ln < 63) && (g < NPB) && (v < N_NODES);
    float dposv = 0.0f, invd = 0.0f;
    int   cnt = 0, ocnt = 0;
    int   er[8];
    // role-0 lane reads fill/deg once per triple; shfl to roles 1-2
    int fv = 0;
    if (active && q == 0) fv = ld_coh_i(&fill[v]);
    {
        int f0 = __shfl(fv, (ln / 3) * 3);        // broadcast from role-0 lane
        if (active) cnt = min(f0, CAP);
    }
    if (active) {
        // two int4 plain loads (16B-aligned: v*96 + q*32); lines fresh
        // (st_coh-written, never plain-read pre-barrier) -> never cached stale
        const int4* pb = (const int4*)&pcsc[v * CAP + q * 8];
        int4 a = pb[0], b = pb[1];
        er[0]=a.x; er[1]=a.y; er[2]=a.z; er[3]=a.w;
        er[4]=b.x; er[5]=b.y; er[6]=b.z; er[7]=b.w;
        if (q == 0) {
            dposv  = fmaxf(demands[v], 0.0f);
            int dv = ld_coh_i(&deg[v]);
            invd   = (dv > 0) ? (1.0f / (float)dv) : 0.0f;  // V[v] unread if deg==0
            ocnt   = ld_coh_i(ofl_cnt);                     // expected 0
            st_coh(&V0[v], dposv * invd);                   // publish V_1
        }
    }
    gbar(grp, ++bar);

    // ---- 9 iterations: predicated gathers + wave shfl reduce, no LDS ----
    #pragma unroll 1
    for (int j = 2; j <= FLOW_ITERS; ++j) {
        const float* Vp = (j & 1) ? V1b : V0;   // j even: read V0, write V1b
        float*       Vn = (j & 1) ? V0 : V1b;
        float p = 0.0f;
        if (active) {
            #pragma unroll
            for (int s = 0; s < 8; ++s)
                if (q * 8 + s < cnt) p += ld_coh(&Vp[er[s]]);   // predicated
        }
        // roles q=0,1,2 are lanes ln, ln+1, ln+2 of the same wave
        float p1 = __shfl_down(p, 1);
        float p2 = __shfl_down(p, 2);
        if (active && q == 0) {
            float acc = dposv + p + p1 + p2;
            if (ocnt > 0) {                     // exactness fallback, ~never
                for (int o = 0; o < ocnt && o < OFL_MAX; ++o)
                    if (ld_coh_i(&ofl_v[o]) == v)
                        acc += ld_coh(&Vp[ld_coh_i(&ofl_row[o])]);
            }
            st_coh(&Vn[v], acc * invd);         // publish V_j
        }
        gbar(grp, ++bar);
    }

    // ---- out[e] = V_10[row_e] (j=10 wrote V1b); float2 stores ----
    if (bld) {
        float2 o2;
        o2.x = ld_coh(&V1b[r2.x]);
        o2.y = ld_coh(&V1b[r2.y]);
        ((float2*)out)[m] = o2;
    }
}

extern "C" void kernel_launch(void* const* d_in, const int* in_sizes, int n_in,
                              void* d_out, int out_size, void* d_ws, size_t ws_size,
                              hipStream_t stream) {
    const float* demands  = (const float*)d_in[1];
    const int*   edge_row = (const int*)d_in[2];
    const int*   edge_col = (const int*)d_in[3];
    float*       out      = (float*)d_out;

    char* ws = (char*)d_ws;
    auto take = [&](size_t bytes) {
        void* p = (void*)ws;
        ws += (bytes + 127) & ~size_t(127);
        return p;
    };
    // ---- zero zone (one 0x00 memset) ----
    char* zone0 = ws;
    int*   deg     = (int*)  take(N_NODES * 4);
    int*   fill    = (int*)  take(N_NODES * 4);
    int*   ofl_cnt = (int*)  take(4);
    int*   grp     = (int*)  take(GLINES * 32 * 4);
    size_t zone0_bytes = (size_t)(ws - zone0);
    // ---- uninitialized zone ----
    float* V0      = (float*)take(N_NODES * 4);
    float* V1b     = (float*)take(N_NODES * 4);
    int*   pcsc    = (int*)  take((size_t)N_NODES * CAP * 4);
    int*   ofl_v   = (int*)  take(OFL_MAX * 4);
    int*   ofl_row = (int*)  take(OFL_MAX * 4);

    hipMemsetAsync(zone0, 0x00, zone0_bytes, stream);
    mcf_fused<<<NBLK, NTHR, 0, stream>>>(demands, edge_row, edge_col, out,
                                         deg, fill, V0, V1b, pcsc,
                                         ofl_cnt, ofl_v, ofl_row, grp);
}

// Round 19
// 122.183 us; speedup vs baseline: 1.0560x; 1.0560x over previous
//
#include <hip/hip_runtime.h>

// SparseMCFModel — output `flow` depends ONLY on demands, edge_row, edge_col.
// w_e = 1/deg(row_e) exactly (softmax over identical logits per segment) -> the
// GAT/GRU/decoder pipeline is dead code. Since w depends on row only:
//   flow_j[e] = V_j[row_e],
//   V_1[v] = relu(d[v])/deg[v],
//   V_j[v] = (relu(d[v]) + sum_{e:col=v} V_{j-1}[row_e]) / deg[v],  j=2..10
//   out[e] = V_10[row_e].
//
// FINAL (r17 config, best validated: 48.3us kernel / 123us dur):
//  - single plain launch, 128 blocks x 1024 threads (all co-resident)
//  - build: int2 edge loads over 782 thr/block (12 waves hide ~900cy atomic
//    latency), deg/fill global atomics (measured cheap, r13), column-local
//    padded CSC (row-only payload, CAP=24 + exact overflow list)
//  - iterations: 3 roles x 8 slots per node on adjacent lanes, predicated
//    ld_coh gathers, __shfl_down reduce, coalesced st_coh publish
//  - sync: relaxed monotone counter over 8 padded lines, zero cache-op
//    (acquire-polling costs ~55us/iter [r2-r4]; 32 lines regresses [r18];
//    256 blocks regresses [r10/r16])
// Ceiling: 9 sequential publish->barrier->gather coherence round-trips =
// latency x dependency-depth floor; HBM 6.7%, VALU 1.4% — no BW/compute
// roofline applies.

#define N_NODES 20000
#define N_EDGES 200000
#define FLOW_ITERS 10
#define NBLK 128
#define NTHR 1024
#define NPB 157                            // nodes per block (128*157 = 20096)
#define CAP 24                             // padded in-edge slots per node
#define NPAIR 100000                       // N_EDGES/2 int2 pairs
#define PPB 782                            // pairs per block (782*128 = 100096)
#define OFL_MAX 4096

__device__ __forceinline__ float ld_coh(const float* p) {
    return __hip_atomic_load(p, __ATOMIC_RELAXED, __HIP_MEMORY_SCOPE_AGENT);
}
__device__ __forceinline__ int ld_coh_i(const int* p) {
    return __hip_atomic_load(p, __ATOMIC_RELAXED, __HIP_MEMORY_SCOPE_AGENT);
}
__device__ __forceinline__ void st_coh(float* p, float v) {
    __hip_atomic_store(p, v, __ATOMIC_RELAXED, __HIP_MEMORY_SCOPE_AGENT);
}
__device__ __forceinline__ void st_coh_i(int* p, int v) {
    __hip_atomic_store(p, v, __ATOMIC_RELAXED, __HIP_MEMORY_SCOPE_AGENT);
}

// Distributed-arrival zero-cache-op barrier (validated r14-r17): arrivals
// spread over 8 padded lines; pollers sum all 8 with independent loads.
// Soundness (r6-r17): __syncthreads drains vmcnt before s_barrier; all
// cross-block mutable data via coherent-point ops or fresh-line plain reads.
__device__ __forceinline__ void gbar(int* grp, int ord) {
    __syncthreads();
    if (threadIdx.x == 0) {
        __hip_atomic_fetch_add(&grp[(blockIdx.x & 7) * 32], 1,
                               __ATOMIC_RELAXED, __HIP_MEMORY_SCOPE_AGENT);
        const int target = NBLK * ord;
        for (;;) {
            int s = 0;
            #pragma unroll
            for (int g = 0; g < 8; ++g)
                s += __hip_atomic_load(&grp[g * 32], __ATOMIC_RELAXED,
                                       __HIP_MEMORY_SCOPE_AGENT);
            if (s >= target) break;
            __builtin_amdgcn_s_sleep(1);
        }
    }
    __syncthreads();
}

__global__ __launch_bounds__(NTHR)
void mcf_fused(const float* __restrict__ demands,
               const int* __restrict__ edge_row,   // int2-aligned
               const int* __restrict__ edge_col,
               float* __restrict__ out,
               int* __restrict__ deg,       // [N]   zeroed by memset
               int* __restrict__ fill,      // [N]   zeroed by memset
               float* __restrict__ V0,      // [N]
               float* __restrict__ V1b,     // [N]
               int* __restrict__ pcsc,      // [N*CAP], [v*CAP + k]
               int* __restrict__ ofl_cnt,   // [1]   zeroed by memset
               int* __restrict__ ofl_v,     // [OFL_MAX]
               int* __restrict__ ofl_row,   // [OFL_MAX]
               int* __restrict__ grp)       // [8*32] zeroed by memset
{
    const int tx = threadIdx.x, bx = blockIdx.x;
    int bar = 0;

    // ---- Build: int2 pair loads over 782 threads (12.2 waves of latency
    //      hiding), deg/fill atomics, column-local placement ----
    const int m = bx * PPB + tx;                  // this thread's pair
    const bool bld = (tx < PPB) && (m < NPAIR);
    int2 r2 = {0, 0};
    if (bld) {
        r2 = ((const int2*)edge_row)[m];
        int2 c2 = ((const int2*)edge_col)[m];
        int rr[2] = {r2.x, r2.y};
        int cc[2] = {c2.x, c2.y};
        #pragma unroll
        for (int i = 0; i < 2; ++i) {
            __hip_atomic_fetch_add(&deg[rr[i]], 1, __ATOMIC_RELAXED, __HIP_MEMORY_SCOPE_AGENT);
            int idx = __hip_atomic_fetch_add(&fill[cc[i]], 1,
                                             __ATOMIC_RELAXED, __HIP_MEMORY_SCOPE_AGENT);
            if (idx < CAP) {
                st_coh_i(&pcsc[cc[i] * CAP + idx], rr[i]);
            } else {
                int o = __hip_atomic_fetch_add(ofl_cnt, 1,
                                               __ATOMIC_RELAXED, __HIP_MEMORY_SCOPE_AGENT);
                if (o < OFL_MAX) { st_coh_i(&ofl_v[o], cc[i]); st_coh_i(&ofl_row[o], rr[i]); }
            }
        }
    }
    gbar(grp, ++bar);

    // ---- Role setup: wave-local triples (21 nodes per 63-lane group) ----
    const int wv = tx >> 6, ln = tx & 63;         // wave, lane
    const int t  = ln / 3, q = ln - 3 * t;        // triple, role (lane 63 idle)
    const int g  = wv * 21 + t;                   // node-in-block (16*21=336>=157)
    const int v  = bx * NPB + g;
    const bool active = (ln < 63) && (g < NPB) && (v < N_NODES);
    float dposv = 0.0f, invd = 0.0f;
    int   cnt = 0, ocnt = 0;
    int   er[8];
    if (active) {
        cnt = min(ld_coh_i(&fill[v]), CAP);
        // two int4 plain loads (16B-aligned: v*96 + q*32); lines fresh
        // (st_coh-written, never plain-read pre-barrier) -> never cached stale
        const int4* pb = (const int4*)&pcsc[v * CAP + q * 8];
        int4 a = pb[0], b = pb[1];
        er[0]=a.x; er[1]=a.y; er[2]=a.z; er[3]=a.w;
        er[4]=b.x; er[5]=b.y; er[6]=b.z; er[7]=b.w;
        if (q == 0) {
            dposv  = fmaxf(demands[v], 0.0f);
            int dv = ld_coh_i(&deg[v]);
            invd   = (dv > 0) ? (1.0f / (float)dv) : 0.0f;  // V[v] unread if deg==0
            ocnt   = ld_coh_i(ofl_cnt);                     // expected 0
            st_coh(&V0[v], dposv * invd);                   // publish V_1
        }
    }
    gbar(grp, ++bar);

    // ---- 9 iterations: predicated gathers + wave shfl reduce, no LDS ----
    #pragma unroll 1
    for (int j = 2; j <= FLOW_ITERS; ++j) {
        const float* Vp = (j & 1) ? V1b : V0;   // j even: read V0, write V1b
        float*       Vn = (j & 1) ? V0 : V1b;
        float p = 0.0f;
        if (active) {
            #pragma unroll
            for (int s = 0; s < 8; ++s)
                if (q * 8 + s < cnt) p += ld_coh(&Vp[er[s]]);   // predicated
        }
        // roles q=0,1,2 are lanes ln, ln+1, ln+2 of the same wave
        float p1 = __shfl_down(p, 1);
        float p2 = __shfl_down(p, 2);
        if (active && q == 0) {
            float acc = dposv + p + p1 + p2;
            if (ocnt > 0) {                     // exactness fallback, ~never
                for (int o = 0; o < ocnt && o < OFL_MAX; ++o)
                    if (ld_coh_i(&ofl_v[o]) == v)
                        acc += ld_coh(&Vp[ld_coh_i(&ofl_row[o])]);
            }
            st_coh(&Vn[v], acc * invd);         // publish V_j
        }
        gbar(grp, ++bar);
    }

    // ---- out[e] = V_10[row_e] (j=10 wrote V1b); float2 stores ----
    if (bld) {
        float2 o2;
        o2.x = ld_coh(&V1b[r2.x]);
        o2.y = ld_coh(&V1b[r2.y]);
        ((float2*)out)[m] = o2;
    }
}

extern "C" void kernel_launch(void* const* d_in, const int* in_sizes, int n_in,
                              void* d_out, int out_size, void* d_ws, size_t ws_size,
                              hipStream_t stream) {
    const float* demands  = (const float*)d_in[1];
    const int*   edge_row = (const int*)d_in[2];
    const int*   edge_col = (const int*)d_in[3];
    float*       out      = (float*)d_out;

    char* ws = (char*)d_ws;
    auto take = [&](size_t bytes) {
        void* p = (void*)ws;
        ws += (bytes + 127) & ~size_t(127);
        return p;
    };
    // ---- zero zone (one 0x00 memset) ----
    char* zone0 = ws;
    int*   deg     = (int*)  take(N_NODES * 4);
    int*   fill    = (int*)  take(N_NODES * 4);
    int*   ofl_cnt = (int*)  take(4);
    int*   grp     = (int*)  take(8 * 32 * 4);
    size_t zone0_bytes = (size_t)(ws - zone0);
    // ---- uninitialized zone ----
    float* V0      = (float*)take(N_NODES * 4);
    float* V1b     = (float*)take(N_NODES * 4);
    int*   pcsc    = (int*)  take((size_t)N_NODES * CAP * 4);
    int*   ofl_v   = (int*)  take(OFL_MAX * 4);
    int*   ofl_row = (int*)  take(OFL_MAX * 4);

    hipMemsetAsync(zone0, 0x00, zone0_bytes, stream);
    mcf_fused<<<NBLK, NTHR, 0, stream>>>(demands, edge_row, edge_col, out,
                                         deg, fill, V0, V1b, pcsc,
                                         ofl_cnt, ofl_v, ofl_row, grp);
}